// Round 8
// baseline (365.618 us; speedup 1.0000x reference)
//
#include <hip/hip_runtime.h>
#include <hip/hip_bf16.h>
#include <math.h>

typedef __bf16 bf16;
typedef __bf16 bf16x4 __attribute__((ext_vector_type(4)));
typedef __bf16 bf16x8 __attribute__((ext_vector_type(8)));
typedef float f32x4 __attribute__((ext_vector_type(4)));
typedef unsigned int u32;

#define MFMA_BF16(a, b, c) __builtin_amdgcn_mfma_f32_16x16x32_bf16(a, b, c, 0, 0, 0)
// async global->LDS, 16B per lane; LDS dest = wave-uniform base + lane*16
#define ASYNC16(g, l)                                                                   \
    __builtin_amdgcn_global_load_lds((const __attribute__((address_space(1))) u32*)(g), \
                                     (__attribute__((address_space(3))) u32*)(l), 16, 0, 0)

// ---------------- transpose + cast fp32 -> bf16 (out[c][r] = in[r][c]) ----------------
__global__ __launch_bounds__(256)
void transpose_cast(const float* __restrict__ in, bf16* __restrict__ out, int rows, int cols) {
    __shared__ float tile[32][33];
    const int tx = threadIdx.x, ty = threadIdx.y;
    const int c0 = blockIdx.x * 32, r0 = blockIdx.y * 32;
    #pragma unroll
    for (int j = 0; j < 4; j++)
        tile[ty + j * 8][tx] = in[(size_t)(r0 + ty + j * 8) * cols + c0 + tx];
    __syncthreads();
    #pragma unroll
    for (int j = 0; j < 4; j++)
        out[(size_t)(c0 + ty + j * 8) * rows + r0 + tx] = (bf16)tile[tx][ty + j * 8];
}

// ---------------- transpose V out of qkv: vt[(b*16+h)*64+d][t] = qkv[b][t][2048+h*64+d] ----------------
__global__ __launch_bounds__(256)
void transpose_v(const bf16* __restrict__ qkv, bf16* __restrict__ vt) {
    __shared__ bf16 tile[32][33];
    const int tx = threadIdx.x, ty = threadIdx.y;  // (32,8)
    const int t0 = blockIdx.x * 32;
    const int d0 = blockIdx.y * 32;
    const int bh = blockIdx.z;
    const int b = bh >> 4, h = bh & 15;
    const bf16* src = qkv + (size_t)b * 2048 * 3072 + 2048 + h * 64;
    #pragma unroll
    for (int j = 0; j < 4; j++)
        tile[ty + j * 8][tx] = src[(size_t)(t0 + ty + j * 8) * 3072 + d0 + tx];
    __syncthreads();
    #pragma unroll
    for (int j = 0; j < 4; j++)
        vt[((size_t)bh * 64 + d0 + ty + j * 8) * 2048 + t0 + tx] = tile[tx][ty + j * 8];
}

// ---------------- LayerNorm fp32 -> bf16, D=1024, one block per row ----------------
__global__ __launch_bounds__(256)
void ln_kernel(const float* __restrict__ x, const float* __restrict__ g,
               const float* __restrict__ bb, bf16* __restrict__ out) {
    const int row = blockIdx.x, tid = threadIdx.x;
    const float4 v = reinterpret_cast<const float4*>(x)[(size_t)row * 256 + tid];
    float s = v.x + v.y + v.z + v.w;
    float sq = v.x * v.x + v.y * v.y + v.z * v.z + v.w * v.w;
    #pragma unroll
    for (int o = 32; o > 0; o >>= 1) { s += __shfl_xor(s, o); sq += __shfl_xor(sq, o); }
    __shared__ float ssum[4], ssq[4];
    const int wave = tid >> 6, lane = tid & 63;
    if (lane == 0) { ssum[wave] = s; ssq[wave] = sq; }
    __syncthreads();
    s = ssum[0] + ssum[1] + ssum[2] + ssum[3];
    sq = ssq[0] + ssq[1] + ssq[2] + ssq[3];
    const float mean = s * (1.0f / 1024.0f);
    const float var = sq * (1.0f / 1024.0f) - mean * mean;
    const float rstd = rsqrtf(var + 1e-5f);
    const float4 gv = reinterpret_cast<const float4*>(g)[tid];
    const float4 bv = reinterpret_cast<const float4*>(bb)[tid];
    bf16x4 o;
    o[0] = (bf16)((v.x - mean) * rstd * gv.x + bv.x);
    o[1] = (bf16)((v.y - mean) * rstd * gv.y + bv.y);
    o[2] = (bf16)((v.z - mean) * rstd * gv.z + bv.z);
    o[3] = (bf16)((v.w - mean) * rstd * gv.w + bv.w);
    reinterpret_cast<bf16x4*>(out)[(size_t)row * 256 + tid] = o;
}

// fast exact-enough GELU: v * sigmoid(1.595769122*(v + 0.044715 v^3)); max dev vs erf-gelu ~3e-4
__device__ __forceinline__ float gelu_fast(float v) {
    const float vv = v * v;
    const float u = v * (1.595769122f + 0.0713548162726f * vv);
    const float t = exp2f(u * -1.4426950408889634f);   // e^{-u}
    return v / (1.0f + t);
}

// ---------------- GEMM: C[M,N] = A[M,K] @ Bt[N,K]^T ----------------
// BK=32, double-buffered LDS, ONE barrier per K-iter (async loads for tile k+1 issued
// right after the barrier, in flight during compute of tile k).
// XOR swizzle: phys 16B-group = logical ^ (row & 3); staging fetches global group
// (lane&3)^((lane>>2)&3) so the fixed global_load_lds write pattern lands swizzled.
// EPI: 0 = bf16 store; 1 = outf = resid + acc (fp32); 2 = gelu bf16
template <int EPI, int BN>
__global__ __launch_bounds__(256)
void gemm_bt(const bf16* __restrict__ A, const bf16* __restrict__ Bt,
             const float* __restrict__ resid, float* __restrict__ outf,
             bf16* __restrict__ outb, int M, int N, int K) {
    constexpr int NB = BN / 32;          // b-frag tiles per wave
    __shared__ bf16 As[2][128][32];
    __shared__ bf16 Bs[2][BN][32];
    const int tid = threadIdx.x;
    const int wave = tid >> 6, lane = tid & 63;
    const int lm = lane & 15, lq = lane >> 4;
    const int wm = (wave >> 1) * 64, wn = (wave & 1) * (BN / 2);
    const int bm = blockIdx.y * 128, bn = blockIdx.x * BN;
    const int srow = lane >> 2;                              // staging row 0..15
    const int sg = (((lane & 3) ^ ((lane >> 2) & 3)) * 8);   // swizzled source col (bf16)
    const int pco = (lq ^ (lm & 3)) * 8;                     // reader phys col (bf16)
    f32x4 acc[4][NB];
    #pragma unroll
    for (int i = 0; i < 4; i++)
        #pragma unroll
        for (int j = 0; j < NB; j++) acc[i][j] = (f32x4){0.f, 0.f, 0.f, 0.f};

    auto stage = [&](int bb, int kt) {
        ASYNC16(A + (size_t)(bm + wave * 32 + srow) * K + kt + sg,      &As[bb][wave * 32][0]);
        ASYNC16(A + (size_t)(bm + wave * 32 + 16 + srow) * K + kt + sg, &As[bb][wave * 32 + 16][0]);
        if (BN == 128) {
            ASYNC16(Bt + (size_t)(bn + wave * 32 + srow) * K + kt + sg,      &Bs[bb][wave * 32][0]);
            ASYNC16(Bt + (size_t)(bn + wave * 32 + 16 + srow) * K + kt + sg, &Bs[bb][wave * 32 + 16][0]);
        } else {
            ASYNC16(Bt + (size_t)(bn + wave * 16 + srow) * K + kt + sg,      &Bs[bb][wave * 16][0]);
        }
    };

    stage(0, 0);
    int cur = 0;
    for (int kt = 0; kt < K; kt += 32) {
        __syncthreads();   // buf[cur] loads drained; prior reads of buf[cur^1] done
        if (kt + 32 < K) stage(cur ^ 1, kt + 32);   // overlap with compute below
        bf16x8 af[4], bfr[NB];
        #pragma unroll
        for (int i = 0; i < 4; i++)
            af[i] = *reinterpret_cast<const bf16x8*>(&As[cur][wm + i * 16 + lm][pco]);
        #pragma unroll
        for (int j = 0; j < NB; j++)
            bfr[j] = *reinterpret_cast<const bf16x8*>(&Bs[cur][wn + j * 16 + lm][pco]);
        #pragma unroll
        for (int i = 0; i < 4; i++)
            #pragma unroll
            for (int j = 0; j < NB; j++)
                acc[i][j] = MFMA_BF16(af[i], bfr[j], acc[i][j]);
        cur ^= 1;
    }

    const int r0 = bm + wm, c0 = bn + wn;
    #pragma unroll
    for (int i = 0; i < 4; i++) {
        #pragma unroll
        for (int j = 0; j < NB; j++) {
            #pragma unroll
            for (int e = 0; e < 4; e++) {
                const int row = r0 + i * 16 + lq * 4 + e;
                const int col = c0 + j * 16 + lm;
                const float v = acc[i][j][e];
                const size_t idx = (size_t)row * N + col;
                if (EPI == 0) {
                    outb[idx] = (bf16)v;
                } else if (EPI == 1) {
                    outf[idx] = resid[idx] + v;
                } else {
                    outb[idx] = (bf16)gelu_fast(v);
                }
            }
        }
    }
}

// ---------------- Flash attention, causal, hd=64, T=2048, H=16 ----------------
// grid (16 pairs, 16 heads, 2 batch), block 256; each block does qt = 31-bx then qt = bx
// Fixed-shift softmax (M=0); row-sum l via MFMA against ones-column B fragment.
__global__ __launch_bounds__(256)
void attn_kernel(const bf16* __restrict__ qkv, const bf16* __restrict__ vt,
                 bf16* __restrict__ y) {
    __shared__ bf16 Ks[64][68];        // [key][hd]; stride 34 dw -> 2-way max on b128
    __shared__ bf16 Vt[64][68];        // [hd][key]
    __shared__ bf16 Ps[4][16][68];     // per-wave P tile [qrow][key]
    const int tid = threadIdx.x, wave = tid >> 6, lane = tid & 63;
    const int lm = lane & 15, lq = lane >> 4;
    const int h = blockIdx.y, b = blockIdx.z;
    const size_t base = (size_t)b * 2048 * 3072;
    const bf16* Kbase = qkv + base + 1024 + h * 64;
    const bf16* Vbase = vt + ((size_t)(b * 16 + h) * 64) * 2048;
    const int skey = tid >> 3, sch = (tid & 7) * 8;
    const float k1 = 0.18033688011112042f;   // 0.125 * log2(e)

    bf16x8 ones;
    #pragma unroll
    for (int j = 0; j < 8; j++) ones[j] = (lm == 0) ? (bf16)1.0f : (bf16)0.0f;

    for (int ph = 0; ph < 2; ph++) {
        const int qt = ph ? (int)blockIdx.x : 31 - (int)blockIdx.x;

        const int qrow = qt * 64 + wave * 16 + lm;
        const bf16* qp = qkv + base + (size_t)qrow * 3072 + h * 64 + lq * 8;
        bf16x8 aq0 = *reinterpret_cast<const bf16x8*>(qp);
        bf16x8 aq1 = *reinterpret_cast<const bf16x8*>(qp + 32);
        #pragma unroll
        for (int j = 0; j < 8; j++) {
            aq0[j] = (bf16)((float)aq0[j] * k1);
            aq1[j] = (bf16)((float)aq1[j] * k1);
        }

        f32x4 Oc[4], Ol;
        #pragma unroll
        for (int nt = 0; nt < 4; nt++) Oc[nt] = (f32x4){0.f, 0.f, 0.f, 0.f};
        Ol = (f32x4){0.f, 0.f, 0.f, 0.f};

        bf16x8 pk0, pk1, pv0, pv1;
        {   // prefetch tile 0
            const bf16* kp = Kbase + (size_t)skey * 3072 + sch;
            pk0 = *reinterpret_cast<const bf16x8*>(kp);
            pk1 = *reinterpret_cast<const bf16x8*>(kp + (size_t)32 * 3072);
            const bf16* vp = Vbase + (size_t)skey * 2048 + sch;
            pv0 = *reinterpret_cast<const bf16x8*>(vp);
            pv1 = *reinterpret_cast<const bf16x8*>(vp + (size_t)32 * 2048);
        }

        for (int kt2 = 0; kt2 <= qt; kt2++) {
            __syncthreads();   // previous iteration/phase LDS reads complete
            *reinterpret_cast<bf16x8*>(&Ks[skey][sch])      = pk0;
            *reinterpret_cast<bf16x8*>(&Ks[skey + 32][sch]) = pk1;
            *reinterpret_cast<bf16x8*>(&Vt[skey][sch])      = pv0;
            *reinterpret_cast<bf16x8*>(&Vt[skey + 32][sch]) = pv1;
            __syncthreads();
            if (kt2 < qt) {   // next-tile loads overlap compute
                const bf16* kp = Kbase + (size_t)((kt2 + 1) * 64 + skey) * 3072 + sch;
                pk0 = *reinterpret_cast<const bf16x8*>(kp);
                pk1 = *reinterpret_cast<const bf16x8*>(kp + (size_t)32 * 3072);
                const bf16* vp = Vbase + (size_t)skey * 2048 + (kt2 + 1) * 64 + sch;
                pv0 = *reinterpret_cast<const bf16x8*>(vp);
                pv1 = *reinterpret_cast<const bf16x8*>(vp + (size_t)32 * 2048);
            }

            f32x4 Sc[4];
            #pragma unroll
            for (int nt = 0; nt < 4; nt++) Sc[nt] = (f32x4){0.f, 0.f, 0.f, 0.f};
            #pragma unroll
            for (int nt = 0; nt < 4; nt++) {
                const bf16x8 bk0 = *reinterpret_cast<const bf16x8*>(&Ks[nt * 16 + lm][lq * 8]);
                const bf16x8 bk1 = *reinterpret_cast<const bf16x8*>(&Ks[nt * 16 + lm][32 + lq * 8]);
                Sc[nt] = MFMA_BF16(aq0, bk0, Sc[nt]);
                Sc[nt] = MFMA_BF16(aq1, bk1, Sc[nt]);
            }

            // fixed-shift softmax: p = exp2(score); masked -> 0
            const int qb = wave * 16 + lq * 4;
            #pragma unroll
            for (int e = 0; e < 4; e++) {
                #pragma unroll
                for (int nt = 0; nt < 4; nt++) {
                    float sv = Sc[nt][e];
                    if (kt2 == qt && (nt * 16 + lm) > (qb + e)) sv = -1e30f;
                    Ps[wave][lq * 4 + e][nt * 16 + lm] = (bf16)exp2f(sv);
                }
            }

            const bf16x8 ap0 = *reinterpret_cast<const bf16x8*>(&Ps[wave][lm][lq * 8]);
            const bf16x8 ap1 = *reinterpret_cast<const bf16x8*>(&Ps[wave][lm][32 + lq * 8]);
            Ol = MFMA_BF16(ap0, ones, Ol);      // row-sum l into column 0
            Ol = MFMA_BF16(ap1, ones, Ol);
            #pragma unroll
            for (int nt = 0; nt < 4; nt++) {
                const bf16x8 bv0 = *reinterpret_cast<const bf16x8*>(&Vt[nt * 16 + lm][lq * 8]);
                const bf16x8 bv1 = *reinterpret_cast<const bf16x8*>(&Vt[nt * 16 + lm][32 + lq * 8]);
                Oc[nt] = MFMA_BF16(ap0, bv0, Oc[nt]);
                Oc[nt] = MFMA_BF16(ap1, bv1, Oc[nt]);
            }
        }

        const int qrow0 = qt * 64 + wave * 16 + lq * 4;
        float inv[4];
        #pragma unroll
        for (int e = 0; e < 4; e++) inv[e] = 1.0f / __shfl(Ol[e], lane & 48);
        #pragma unroll
        for (int nt = 0; nt < 4; nt++)
            #pragma unroll
            for (int e = 0; e < 4; e++) {
                const int row = qrow0 + e;
                y[((size_t)b * 2048 + row) * 1024 + h * 64 + nt * 16 + lm] = (bf16)(Oc[nt][e] * inv[e]);
            }
    }
}

// ---------------- launcher ----------------
extern "C" void kernel_launch(void* const* d_in, const int* in_sizes, int n_in,
                              void* d_out, int out_size, void* d_ws, size_t ws_size,
                              hipStream_t stream) {
    const float* x     = (const float*)d_in[0];
    const float* Wqkv  = (const float*)d_in[1];
    const float* Wproj = (const float*)d_in[2];
    const float* Wfc1  = (const float*)d_in[3];
    const float* Wfc2  = (const float*)d_in[4];
    const float* ln1g  = (const float*)d_in[5];
    const float* ln1b  = (const float*)d_in[6];
    const float* ln2g  = (const float*)d_in[7];
    const float* ln2b  = (const float*)d_in[8];
    float* out = (float*)d_out;
    char* ws = (char*)d_ws;

    bf16*  Wqkvt  = (bf16*)(ws);                  //  6 MB [3072][1024]
    bf16*  Wprojt = (bf16*)(ws + 6291456);        //  2 MB [1024][1024]
    bf16*  Wfc1t  = (bf16*)(ws + 8388608);        //  8 MB [4096][1024]
    bf16*  Wfc2t  = (bf16*)(ws + 16777216);       //  8 MB [1024][4096]
    bf16*  hb     = (bf16*)(ws + 25165824);       //  8 MB LN out; dead after qkv GEMM
    bf16*  vt     = (bf16*)(ws + 25165824);       //  8 MB V^T (aliases hb; reused for LN2)
    bf16*  qkv    = (bf16*)(ws + 33554432);       // 24 MB [4096][3072]
    bf16*  yb     = (bf16*)(ws + 58720256);       //  8 MB attn out [4096][1024]
    float* x1     = (float*)(ws + 67108864);      // 16 MB residual fp32
    bf16*  h3     = (bf16*)(ws + 33554432);       // 32 MB gelu out (aliases dead qkv+yb)

    const dim3 tb(32, 8);
    transpose_cast<<<dim3(96, 32), tb, 0, stream>>>(Wqkv, Wqkvt, 1024, 3072);
    transpose_cast<<<dim3(32, 32), tb, 0, stream>>>(Wproj, Wprojt, 1024, 1024);
    transpose_cast<<<dim3(128, 32), tb, 0, stream>>>(Wfc1, Wfc1t, 1024, 4096);
    transpose_cast<<<dim3(32, 128), tb, 0, stream>>>(Wfc2, Wfc2t, 4096, 1024);

    ln_kernel<<<dim3(4096), dim3(256), 0, stream>>>(x, ln1g, ln1b, hb);
    gemm_bt<0, 128><<<dim3(24, 32), dim3(256), 0, stream>>>(hb, Wqkvt, nullptr, nullptr, qkv, 4096, 3072, 1024);
    transpose_v<<<dim3(64, 2, 32), tb, 0, stream>>>(qkv, vt);
    attn_kernel<<<dim3(16, 16, 2), dim3(256), 0, stream>>>(qkv, vt, yb);
    gemm_bt<1, 64><<<dim3(16, 32), dim3(256), 0, stream>>>(yb, Wprojt, x, x1, nullptr, 4096, 1024, 1024);
    ln_kernel<<<dim3(4096), dim3(256), 0, stream>>>(x1, ln2g, ln2b, hb);
    gemm_bt<2, 128><<<dim3(32, 32), dim3(256), 0, stream>>>(hb, Wfc1t, nullptr, nullptr, h3, 4096, 4096, 1024);
    gemm_bt<1, 64><<<dim3(16, 32), dim3(256), 0, stream>>>(h3, Wfc2t, x1, out, nullptr, 4096, 1024, 4096);
}

// Round 9
// 361.856 us; speedup vs baseline: 1.0104x; 1.0104x over previous
//
#include <hip/hip_runtime.h>
#include <hip/hip_bf16.h>
#include <math.h>

typedef __bf16 bf16;
typedef __bf16 bf16x4 __attribute__((ext_vector_type(4)));
typedef __bf16 bf16x8 __attribute__((ext_vector_type(8)));
typedef float f32x4 __attribute__((ext_vector_type(4)));
typedef unsigned int u32;

#define MFMA_BF16(a, b, c) __builtin_amdgcn_mfma_f32_16x16x32_bf16(a, b, c, 0, 0, 0)
// async global->LDS, 16B per lane; LDS dest = wave-uniform base + lane*16
#define ASYNC16(g, l)                                                                   \
    __builtin_amdgcn_global_load_lds((const __attribute__((address_space(1))) u32*)(g), \
                                     (__attribute__((address_space(3))) u32*)(l), 16, 0, 0)

// ---------------- transpose + cast fp32 -> bf16 (out[c][r] = in[r][c]) ----------------
__global__ __launch_bounds__(256)
void transpose_cast(const float* __restrict__ in, bf16* __restrict__ out, int rows, int cols) {
    __shared__ float tile[32][33];
    const int tx = threadIdx.x, ty = threadIdx.y;
    const int c0 = blockIdx.x * 32, r0 = blockIdx.y * 32;
    #pragma unroll
    for (int j = 0; j < 4; j++)
        tile[ty + j * 8][tx] = in[(size_t)(r0 + ty + j * 8) * cols + c0 + tx];
    __syncthreads();
    #pragma unroll
    for (int j = 0; j < 4; j++)
        out[(size_t)(c0 + ty + j * 8) * rows + r0 + tx] = (bf16)tile[tx][ty + j * 8];
}

// ---------------- transpose V out of qkv: vt[(b*16+h)*64+d][t] = qkv[b][t][2048+h*64+d] ----------------
__global__ __launch_bounds__(256)
void transpose_v(const bf16* __restrict__ qkv, bf16* __restrict__ vt) {
    __shared__ bf16 tile[32][33];
    const int tx = threadIdx.x, ty = threadIdx.y;  // (32,8)
    const int t0 = blockIdx.x * 32;
    const int d0 = blockIdx.y * 32;
    const int bh = blockIdx.z;
    const int b = bh >> 4, h = bh & 15;
    const bf16* src = qkv + (size_t)b * 2048 * 3072 + 2048 + h * 64;
    #pragma unroll
    for (int j = 0; j < 4; j++)
        tile[ty + j * 8][tx] = src[(size_t)(t0 + ty + j * 8) * 3072 + d0 + tx];
    __syncthreads();
    #pragma unroll
    for (int j = 0; j < 4; j++)
        vt[((size_t)bh * 64 + d0 + ty + j * 8) * 2048 + t0 + tx] = tile[tx][ty + j * 8];
}

// ---------------- LayerNorm fp32 -> bf16, D=1024, one block per row ----------------
__global__ __launch_bounds__(256)
void ln_kernel(const float* __restrict__ x, const float* __restrict__ g,
               const float* __restrict__ bb, bf16* __restrict__ out) {
    const int row = blockIdx.x, tid = threadIdx.x;
    const float4 v = reinterpret_cast<const float4*>(x)[(size_t)row * 256 + tid];
    float s = v.x + v.y + v.z + v.w;
    float sq = v.x * v.x + v.y * v.y + v.z * v.z + v.w * v.w;
    #pragma unroll
    for (int o = 32; o > 0; o >>= 1) { s += __shfl_xor(s, o); sq += __shfl_xor(sq, o); }
    __shared__ float ssum[4], ssq[4];
    const int wave = tid >> 6, lane = tid & 63;
    if (lane == 0) { ssum[wave] = s; ssq[wave] = sq; }
    __syncthreads();
    s = ssum[0] + ssum[1] + ssum[2] + ssum[3];
    sq = ssq[0] + ssq[1] + ssq[2] + ssq[3];
    const float mean = s * (1.0f / 1024.0f);
    const float var = sq * (1.0f / 1024.0f) - mean * mean;
    const float rstd = rsqrtf(var + 1e-5f);
    const float4 gv = reinterpret_cast<const float4*>(g)[tid];
    const float4 bv = reinterpret_cast<const float4*>(bb)[tid];
    bf16x4 o;
    o[0] = (bf16)((v.x - mean) * rstd * gv.x + bv.x);
    o[1] = (bf16)((v.y - mean) * rstd * gv.y + bv.y);
    o[2] = (bf16)((v.z - mean) * rstd * gv.z + bv.z);
    o[3] = (bf16)((v.w - mean) * rstd * gv.w + bv.w);
    reinterpret_cast<bf16x4*>(out)[(size_t)row * 256 + tid] = o;
}

// fast exact-enough GELU: v * sigmoid(1.595769122*(v + 0.044715 v^3)); max dev vs erf-gelu ~3e-4
__device__ __forceinline__ float gelu_fast(float v) {
    const float vv = v * v;
    const float u = v * (1.595769122f + 0.0713548162726f * vv);
    const float t = exp2f(u * -1.4426950408889634f);   // e^{-u}
    return v / (1.0f + t);
}

// ---------------- GEMM: C[M,N] = A[M,K] @ Bt[N,K]^T ----------------
// BK=32, double-buffered LDS, ONE barrier per K-iter.
// Swizzle (period-8 in m): logical k-chunk kc of row m lives at phys slot kc ^ ((m>>1)&3).
// Staging lane fetches global group (lane&3)^((lane>>3)&3); readers use lq ^ ((lm>>1)&3).
// This kills the stride-4 lane collisions of the previous (m&3) swizzle (R8: 6.29M conflicts).
// EPI: 0 = bf16 store; 1 = outf = resid + acc (fp32); 2 = gelu bf16
template <int EPI, int BN>
__global__ __launch_bounds__(256)
void gemm_bt(const bf16* __restrict__ A, const bf16* __restrict__ Bt,
             const float* __restrict__ resid, float* __restrict__ outf,
             bf16* __restrict__ outb, int M, int N, int K) {
    constexpr int NB = BN / 32;          // b-frag tiles per wave
    __shared__ bf16 As[2][128][32];
    __shared__ bf16 Bs[2][BN][32];
    const int tid = threadIdx.x;
    const int wave = tid >> 6, lane = tid & 63;
    const int lm = lane & 15, lq = lane >> 4;
    const int wm = (wave >> 1) * 64, wn = (wave & 1) * (BN / 2);
    const int bm = blockIdx.y * 128, bn = blockIdx.x * BN;
    const int srow = lane >> 2;                              // staging row 0..15
    const int sg = (((lane & 3) ^ ((lane >> 3) & 3)) * 8);   // swizzled source col (bf16)
    const int pco = (lq ^ ((lm >> 1) & 3)) * 8;              // reader phys col (bf16)
    f32x4 acc[4][NB];
    #pragma unroll
    for (int i = 0; i < 4; i++)
        #pragma unroll
        for (int j = 0; j < NB; j++) acc[i][j] = (f32x4){0.f, 0.f, 0.f, 0.f};

    auto stage = [&](int bb, int kt) {
        ASYNC16(A + (size_t)(bm + wave * 32 + srow) * K + kt + sg,      &As[bb][wave * 32][0]);
        ASYNC16(A + (size_t)(bm + wave * 32 + 16 + srow) * K + kt + sg, &As[bb][wave * 32 + 16][0]);
        if (BN == 128) {
            ASYNC16(Bt + (size_t)(bn + wave * 32 + srow) * K + kt + sg,      &Bs[bb][wave * 32][0]);
            ASYNC16(Bt + (size_t)(bn + wave * 32 + 16 + srow) * K + kt + sg, &Bs[bb][wave * 32 + 16][0]);
        } else {
            ASYNC16(Bt + (size_t)(bn + wave * 16 + srow) * K + kt + sg,      &Bs[bb][wave * 16][0]);
        }
    };

    stage(0, 0);
    int cur = 0;
    for (int kt = 0; kt < K; kt += 32) {
        __syncthreads();   // buf[cur] loads drained; prior reads of buf[cur^1] done
        if (kt + 32 < K) stage(cur ^ 1, kt + 32);   // overlap with compute below
        bf16x8 af[4], bfr[NB];
        #pragma unroll
        for (int i = 0; i < 4; i++)
            af[i] = *reinterpret_cast<const bf16x8*>(&As[cur][wm + i * 16 + lm][pco]);
        #pragma unroll
        for (int j = 0; j < NB; j++)
            bfr[j] = *reinterpret_cast<const bf16x8*>(&Bs[cur][wn + j * 16 + lm][pco]);
        #pragma unroll
        for (int i = 0; i < 4; i++)
            #pragma unroll
            for (int j = 0; j < NB; j++)
                acc[i][j] = MFMA_BF16(af[i], bfr[j], acc[i][j]);
        cur ^= 1;
    }

    const int r0 = bm + wm, c0 = bn + wn;
    #pragma unroll
    for (int i = 0; i < 4; i++) {
        #pragma unroll
        for (int j = 0; j < NB; j++) {
            #pragma unroll
            for (int e = 0; e < 4; e++) {
                const int row = r0 + i * 16 + lq * 4 + e;
                const int col = c0 + j * 16 + lm;
                const float v = acc[i][j][e];
                const size_t idx = (size_t)row * N + col;
                if (EPI == 0) {
                    outb[idx] = (bf16)v;
                } else if (EPI == 1) {
                    outf[idx] = resid[idx] + v;
                } else {
                    outb[idx] = (bf16)gelu_fast(v);
                }
            }
        }
    }
}

// ---------------- Flash attention, causal, hd=64, T=2048, H=16 ----------------
// grid (16 pairs, 16 heads, 2 batch), block 256; each block does qt = 31-bx then qt = bx
// Fixed-shift softmax (M=0); row-sum l via MFMA against ones-column B fragment.
__global__ __launch_bounds__(256)
void attn_kernel(const bf16* __restrict__ qkv, const bf16* __restrict__ vt,
                 bf16* __restrict__ y) {
    __shared__ bf16 Ks[64][68];        // [key][hd]; stride 34 dw -> 2-way max on b128
    __shared__ bf16 Vt[64][68];        // [hd][key]
    __shared__ bf16 Ps[4][16][68];     // per-wave P tile [qrow][key]
    const int tid = threadIdx.x, wave = tid >> 6, lane = tid & 63;
    const int lm = lane & 15, lq = lane >> 4;
    const int h = blockIdx.y, b = blockIdx.z;
    const size_t base = (size_t)b * 2048 * 3072;
    const bf16* Kbase = qkv + base + 1024 + h * 64;
    const bf16* Vbase = vt + ((size_t)(b * 16 + h) * 64) * 2048;
    const int skey = tid >> 3, sch = (tid & 7) * 8;
    const float k1 = 0.18033688011112042f;   // 0.125 * log2(e)

    bf16x8 ones;
    #pragma unroll
    for (int j = 0; j < 8; j++) ones[j] = (lm == 0) ? (bf16)1.0f : (bf16)0.0f;

    for (int ph = 0; ph < 2; ph++) {
        const int qt = ph ? (int)blockIdx.x : 31 - (int)blockIdx.x;

        const int qrow = qt * 64 + wave * 16 + lm;
        const bf16* qp = qkv + base + (size_t)qrow * 3072 + h * 64 + lq * 8;
        bf16x8 aq0 = *reinterpret_cast<const bf16x8*>(qp);
        bf16x8 aq1 = *reinterpret_cast<const bf16x8*>(qp + 32);
        #pragma unroll
        for (int j = 0; j < 8; j++) {
            aq0[j] = (bf16)((float)aq0[j] * k1);
            aq1[j] = (bf16)((float)aq1[j] * k1);
        }

        f32x4 Oc[4], Ol;
        #pragma unroll
        for (int nt = 0; nt < 4; nt++) Oc[nt] = (f32x4){0.f, 0.f, 0.f, 0.f};
        Ol = (f32x4){0.f, 0.f, 0.f, 0.f};

        bf16x8 pk0, pk1, pv0, pv1;
        {   // prefetch tile 0
            const bf16* kp = Kbase + (size_t)skey * 3072 + sch;
            pk0 = *reinterpret_cast<const bf16x8*>(kp);
            pk1 = *reinterpret_cast<const bf16x8*>(kp + (size_t)32 * 3072);
            const bf16* vp = Vbase + (size_t)skey * 2048 + sch;
            pv0 = *reinterpret_cast<const bf16x8*>(vp);
            pv1 = *reinterpret_cast<const bf16x8*>(vp + (size_t)32 * 2048);
        }

        for (int kt2 = 0; kt2 <= qt; kt2++) {
            __syncthreads();   // previous iteration/phase LDS reads complete
            *reinterpret_cast<bf16x8*>(&Ks[skey][sch])      = pk0;
            *reinterpret_cast<bf16x8*>(&Ks[skey + 32][sch]) = pk1;
            *reinterpret_cast<bf16x8*>(&Vt[skey][sch])      = pv0;
            *reinterpret_cast<bf16x8*>(&Vt[skey + 32][sch]) = pv1;
            __syncthreads();
            if (kt2 < qt) {   // next-tile loads overlap compute
                const bf16* kp = Kbase + (size_t)((kt2 + 1) * 64 + skey) * 3072 + sch;
                pk0 = *reinterpret_cast<const bf16x8*>(kp);
                pk1 = *reinterpret_cast<const bf16x8*>(kp + (size_t)32 * 3072);
                const bf16* vp = Vbase + (size_t)skey * 2048 + (kt2 + 1) * 64 + sch;
                pv0 = *reinterpret_cast<const bf16x8*>(vp);
                pv1 = *reinterpret_cast<const bf16x8*>(vp + (size_t)32 * 2048);
            }

            f32x4 Sc[4];
            #pragma unroll
            for (int nt = 0; nt < 4; nt++) Sc[nt] = (f32x4){0.f, 0.f, 0.f, 0.f};
            #pragma unroll
            for (int nt = 0; nt < 4; nt++) {
                const bf16x8 bk0 = *reinterpret_cast<const bf16x8*>(&Ks[nt * 16 + lm][lq * 8]);
                const bf16x8 bk1 = *reinterpret_cast<const bf16x8*>(&Ks[nt * 16 + lm][32 + lq * 8]);
                Sc[nt] = MFMA_BF16(aq0, bk0, Sc[nt]);
                Sc[nt] = MFMA_BF16(aq1, bk1, Sc[nt]);
            }

            // fixed-shift softmax: p = exp2(score); masked -> 0
            const int qb = wave * 16 + lq * 4;
            #pragma unroll
            for (int e = 0; e < 4; e++) {
                #pragma unroll
                for (int nt = 0; nt < 4; nt++) {
                    float sv = Sc[nt][e];
                    if (kt2 == qt && (nt * 16 + lm) > (qb + e)) sv = -1e30f;
                    Ps[wave][lq * 4 + e][nt * 16 + lm] = (bf16)exp2f(sv);
                }
            }

            const bf16x8 ap0 = *reinterpret_cast<const bf16x8*>(&Ps[wave][lm][lq * 8]);
            const bf16x8 ap1 = *reinterpret_cast<const bf16x8*>(&Ps[wave][lm][32 + lq * 8]);
            Ol = MFMA_BF16(ap0, ones, Ol);      // row-sum l into column 0
            Ol = MFMA_BF16(ap1, ones, Ol);
            #pragma unroll
            for (int nt = 0; nt < 4; nt++) {
                const bf16x8 bv0 = *reinterpret_cast<const bf16x8*>(&Vt[nt * 16 + lm][lq * 8]);
                const bf16x8 bv1 = *reinterpret_cast<const bf16x8*>(&Vt[nt * 16 + lm][32 + lq * 8]);
                Oc[nt] = MFMA_BF16(ap0, bv0, Oc[nt]);
                Oc[nt] = MFMA_BF16(ap1, bv1, Oc[nt]);
            }
        }

        const int qrow0 = qt * 64 + wave * 16 + lq * 4;
        float inv[4];
        #pragma unroll
        for (int e = 0; e < 4; e++) inv[e] = 1.0f / __shfl(Ol[e], lane & 48);
        #pragma unroll
        for (int nt = 0; nt < 4; nt++)
            #pragma unroll
            for (int e = 0; e < 4; e++) {
                const int row = qrow0 + e;
                y[((size_t)b * 2048 + row) * 1024 + h * 64 + nt * 16 + lm] = (bf16)(Oc[nt][e] * inv[e]);
            }
    }
}

// ---------------- launcher ----------------
extern "C" void kernel_launch(void* const* d_in, const int* in_sizes, int n_in,
                              void* d_out, int out_size, void* d_ws, size_t ws_size,
                              hipStream_t stream) {
    const float* x     = (const float*)d_in[0];
    const float* Wqkv  = (const float*)d_in[1];
    const float* Wproj = (const float*)d_in[2];
    const float* Wfc1  = (const float*)d_in[3];
    const float* Wfc2  = (const float*)d_in[4];
    const float* ln1g  = (const float*)d_in[5];
    const float* ln1b  = (const float*)d_in[6];
    const float* ln2g  = (const float*)d_in[7];
    const float* ln2b  = (const float*)d_in[8];
    float* out = (float*)d_out;
    char* ws = (char*)d_ws;

    bf16*  Wqkvt  = (bf16*)(ws);                  //  6 MB [3072][1024]
    bf16*  Wprojt = (bf16*)(ws + 6291456);        //  2 MB [1024][1024]
    bf16*  Wfc1t  = (bf16*)(ws + 8388608);        //  8 MB [4096][1024]
    bf16*  Wfc2t  = (bf16*)(ws + 16777216);       //  8 MB [1024][4096]
    bf16*  hb     = (bf16*)(ws + 25165824);       //  8 MB LN out; dead after qkv GEMM
    bf16*  vt     = (bf16*)(ws + 25165824);       //  8 MB V^T (aliases hb; reused for LN2)
    bf16*  qkv    = (bf16*)(ws + 33554432);       // 24 MB [4096][3072]
    bf16*  yb     = (bf16*)(ws + 58720256);       //  8 MB attn out [4096][1024]
    float* x1     = (float*)(ws + 67108864);      // 16 MB residual fp32
    bf16*  h3     = (bf16*)(ws + 33554432);       // 32 MB gelu out (aliases dead qkv+yb)

    const dim3 tb(32, 8);
    transpose_cast<<<dim3(96, 32), tb, 0, stream>>>(Wqkv, Wqkvt, 1024, 3072);
    transpose_cast<<<dim3(32, 32), tb, 0, stream>>>(Wproj, Wprojt, 1024, 1024);
    transpose_cast<<<dim3(128, 32), tb, 0, stream>>>(Wfc1, Wfc1t, 1024, 4096);
    transpose_cast<<<dim3(32, 128), tb, 0, stream>>>(Wfc2, Wfc2t, 4096, 1024);

    ln_kernel<<<dim3(4096), dim3(256), 0, stream>>>(x, ln1g, ln1b, hb);
    gemm_bt<0, 128><<<dim3(24, 32), dim3(256), 0, stream>>>(hb, Wqkvt, nullptr, nullptr, qkv, 4096, 3072, 1024);
    transpose_v<<<dim3(64, 2, 32), tb, 0, stream>>>(qkv, vt);
    attn_kernel<<<dim3(16, 16, 2), dim3(256), 0, stream>>>(qkv, vt, yb);
    gemm_bt<1, 64><<<dim3(16, 32), dim3(256), 0, stream>>>(yb, Wprojt, x, x1, nullptr, 4096, 1024, 1024);
    ln_kernel<<<dim3(4096), dim3(256), 0, stream>>>(x1, ln2g, ln2b, hb);
    gemm_bt<2, 128><<<dim3(32, 32), dim3(256), 0, stream>>>(hb, Wfc1t, nullptr, nullptr, h3, 4096, 4096, 1024);
    gemm_bt<1, 64><<<dim3(16, 32), dim3(256), 0, stream>>>(h3, Wfc2t, x1, out, nullptr, 4096, 1024, 4096);
}

// Round 10
// 347.796 us; speedup vs baseline: 1.0512x; 1.0404x over previous
//
#include <hip/hip_runtime.h>
#include <hip/hip_bf16.h>
#include <math.h>

typedef __bf16 bf16;
typedef __bf16 bf16x4 __attribute__((ext_vector_type(4)));
typedef __bf16 bf16x8 __attribute__((ext_vector_type(8)));
typedef float f32x4 __attribute__((ext_vector_type(4)));
typedef unsigned int u32;

#define MFMA_BF16(a, b, c) __builtin_amdgcn_mfma_f32_16x16x32_bf16(a, b, c, 0, 0, 0)
// async global->LDS, 16B per lane; LDS dest = wave-uniform base + lane*16
#define ASYNC16(g, l)                                                                   \
    __builtin_amdgcn_global_load_lds((const __attribute__((address_space(1))) u32*)(g), \
                                     (__attribute__((address_space(3))) u32*)(l), 16, 0, 0)

// ---------------- transpose + cast fp32 -> bf16 (out[c][r] = in[r][c]) ----------------
__global__ __launch_bounds__(256)
void transpose_cast(const float* __restrict__ in, bf16* __restrict__ out, int rows, int cols) {
    __shared__ float tile[32][33];
    const int tx = threadIdx.x, ty = threadIdx.y;
    const int c0 = blockIdx.x * 32, r0 = blockIdx.y * 32;
    #pragma unroll
    for (int j = 0; j < 4; j++)
        tile[ty + j * 8][tx] = in[(size_t)(r0 + ty + j * 8) * cols + c0 + tx];
    __syncthreads();
    #pragma unroll
    for (int j = 0; j < 4; j++)
        out[(size_t)(c0 + ty + j * 8) * rows + r0 + tx] = (bf16)tile[tx][ty + j * 8];
}

// ---------------- transpose V out of qkv: vt[(b*16+h)*64+d][t] = qkv[b][t][2048+h*64+d] ----------------
__global__ __launch_bounds__(256)
void transpose_v(const bf16* __restrict__ qkv, bf16* __restrict__ vt) {
    __shared__ bf16 tile[32][33];
    const int tx = threadIdx.x, ty = threadIdx.y;  // (32,8)
    const int t0 = blockIdx.x * 32;
    const int d0 = blockIdx.y * 32;
    const int bh = blockIdx.z;
    const int b = bh >> 4, h = bh & 15;
    const bf16* src = qkv + (size_t)b * 2048 * 3072 + 2048 + h * 64;
    #pragma unroll
    for (int j = 0; j < 4; j++)
        tile[ty + j * 8][tx] = src[(size_t)(t0 + ty + j * 8) * 3072 + d0 + tx];
    __syncthreads();
    #pragma unroll
    for (int j = 0; j < 4; j++)
        vt[((size_t)bh * 64 + d0 + ty + j * 8) * 2048 + t0 + tx] = tile[tx][ty + j * 8];
}

// ---------------- LayerNorm fp32 -> bf16, D=1024, one block per row ----------------
__global__ __launch_bounds__(256)
void ln_kernel(const float* __restrict__ x, const float* __restrict__ g,
               const float* __restrict__ bb, bf16* __restrict__ out) {
    const int row = blockIdx.x, tid = threadIdx.x;
    const float4 v = reinterpret_cast<const float4*>(x)[(size_t)row * 256 + tid];
    float s = v.x + v.y + v.z + v.w;
    float sq = v.x * v.x + v.y * v.y + v.z * v.z + v.w * v.w;
    #pragma unroll
    for (int o = 32; o > 0; o >>= 1) { s += __shfl_xor(s, o); sq += __shfl_xor(sq, o); }
    __shared__ float ssum[4], ssq[4];
    const int wave = tid >> 6, lane = tid & 63;
    if (lane == 0) { ssum[wave] = s; ssq[wave] = sq; }
    __syncthreads();
    s = ssum[0] + ssum[1] + ssum[2] + ssum[3];
    sq = ssq[0] + ssq[1] + ssq[2] + ssq[3];
    const float mean = s * (1.0f / 1024.0f);
    const float var = sq * (1.0f / 1024.0f) - mean * mean;
    const float rstd = rsqrtf(var + 1e-5f);
    const float4 gv = reinterpret_cast<const float4*>(g)[tid];
    const float4 bv = reinterpret_cast<const float4*>(bb)[tid];
    bf16x4 o;
    o[0] = (bf16)((v.x - mean) * rstd * gv.x + bv.x);
    o[1] = (bf16)((v.y - mean) * rstd * gv.y + bv.y);
    o[2] = (bf16)((v.z - mean) * rstd * gv.z + bv.z);
    o[3] = (bf16)((v.w - mean) * rstd * gv.w + bv.w);
    reinterpret_cast<bf16x4*>(out)[(size_t)row * 256 + tid] = o;
}

// fast exact-enough GELU: v * sigmoid(1.595769122*(v + 0.044715 v^3)); max dev vs erf-gelu ~3e-4
__device__ __forceinline__ float gelu_fast(float v) {
    const float vv = v * v;
    const float u = v * (1.595769122f + 0.0713548162726f * vv);
    const float t = exp2f(u * -1.4426950408889634f);   // e^{-u}
    return v / (1.0f + t);
}

// ---------------- GEMM (BN=128): BK=32, double-buffered, one barrier/iter ----------------
// Swizzle (period-8): phys 16B-group = kc ^ ((m>>1)&3); staging fetches (lane&3)^((lane>>3)&3).
// EPI: 0 = bf16 store; 2 = gelu bf16
template <int EPI>
__global__ __launch_bounds__(256)
void gemm_bt(const bf16* __restrict__ A, const bf16* __restrict__ Bt,
             bf16* __restrict__ outb, int M, int N, int K) {
    __shared__ bf16 As[2][128][32];
    __shared__ bf16 Bs[2][128][32];
    const int tid = threadIdx.x;
    const int wave = tid >> 6, lane = tid & 63;
    const int lm = lane & 15, lq = lane >> 4;
    const int wm = (wave >> 1) * 64, wn = (wave & 1) * 64;
    const int bm = blockIdx.y * 128, bn = blockIdx.x * 128;
    const int srow = lane >> 2;                              // staging row 0..15
    const int sg = (((lane & 3) ^ ((lane >> 3) & 3)) * 8);   // swizzled source col (bf16)
    const int pco = (lq ^ ((lm >> 1) & 3)) * 8;              // reader phys col (bf16)
    f32x4 acc[4][4];
    #pragma unroll
    for (int i = 0; i < 4; i++)
        #pragma unroll
        for (int j = 0; j < 4; j++) acc[i][j] = (f32x4){0.f, 0.f, 0.f, 0.f};

    auto stage = [&](int bb, int kt) {
        ASYNC16(A + (size_t)(bm + wave * 32 + srow) * K + kt + sg,      &As[bb][wave * 32][0]);
        ASYNC16(A + (size_t)(bm + wave * 32 + 16 + srow) * K + kt + sg, &As[bb][wave * 32 + 16][0]);
        ASYNC16(Bt + (size_t)(bn + wave * 32 + srow) * K + kt + sg,      &Bs[bb][wave * 32][0]);
        ASYNC16(Bt + (size_t)(bn + wave * 32 + 16 + srow) * K + kt + sg, &Bs[bb][wave * 32 + 16][0]);
    };

    stage(0, 0);
    int cur = 0;
    for (int kt = 0; kt < K; kt += 32) {
        __syncthreads();
        if (kt + 32 < K) stage(cur ^ 1, kt + 32);
        bf16x8 af[4], bfr[4];
        #pragma unroll
        for (int i = 0; i < 4; i++)
            af[i] = *reinterpret_cast<const bf16x8*>(&As[cur][wm + i * 16 + lm][pco]);
        #pragma unroll
        for (int j = 0; j < 4; j++)
            bfr[j] = *reinterpret_cast<const bf16x8*>(&Bs[cur][wn + j * 16 + lm][pco]);
        #pragma unroll
        for (int i = 0; i < 4; i++)
            #pragma unroll
            for (int j = 0; j < 4; j++)
                acc[i][j] = MFMA_BF16(af[i], bfr[j], acc[i][j]);
        cur ^= 1;
    }

    const int r0 = bm + wm, c0 = bn + wn;
    #pragma unroll
    for (int i = 0; i < 4; i++)
        #pragma unroll
        for (int j = 0; j < 4; j++)
            #pragma unroll
            for (int e = 0; e < 4; e++) {
                const int row = r0 + i * 16 + lq * 4 + e;
                const int col = c0 + j * 16 + lm;
                const float v = acc[i][j][e];
                const size_t idx = (size_t)row * N + col;
                if (EPI == 0) outb[idx] = (bf16)v;
                else          outb[idx] = (bf16)gelu_fast(v);
            }
}

// ---------------- GEMM (BN=64): BK=64, double-buffered, one barrier/iter ----------------
// R7's proven conflict-free 8-wide XOR layout (64B rows): phys group = kc ^ (m&7);
// staging lane fetches global group (lane&7)^(lane>>3). 48 KB LDS.
// EPI1 epilogue: outf = resid + acc (fp32)
__global__ __launch_bounds__(256)
void gemm_bt64(const bf16* __restrict__ A, const bf16* __restrict__ Bt,
               const float* __restrict__ resid, float* __restrict__ outf,
               int M, int N, int K) {
    __shared__ bf16 As[2][128][64];
    __shared__ bf16 Bs[2][64][64];
    const int tid = threadIdx.x;
    const int wave = tid >> 6, lane = tid & 63;
    const int lm = lane & 15, lq = lane >> 4;
    const int wm = (wave >> 1) * 64, wn = (wave & 1) * 32;
    const int bm = blockIdx.y * 128, bn = blockIdx.x * 64;
    const int lr8 = lane >> 3;                       // row 0..7 within 8-row cluster
    const int lg  = ((lane & 7) ^ lr8) * 8;          // swizzled global col (bf16)
    const int sa  = lm & 7;
    int co[2];
    co[0] = (lq ^ sa) * 8;                           // phys col, k-chunk 0
    co[1] = ((lq ^ 4) ^ sa) * 8;                     // phys col, k-chunk 1
    f32x4 acc[4][2];
    #pragma unroll
    for (int i = 0; i < 4; i++)
        #pragma unroll
        for (int j = 0; j < 2; j++) acc[i][j] = (f32x4){0.f, 0.f, 0.f, 0.f};

    auto stage = [&](int bb, int kt) {
        #pragma unroll
        for (int s = 0; s < 4; s++)
            ASYNC16(A + (size_t)(bm + wave * 32 + s * 8 + lr8) * K + kt + lg, &As[bb][wave * 32 + s * 8][0]);
        #pragma unroll
        for (int s = 0; s < 2; s++)
            ASYNC16(Bt + (size_t)(bn + wave * 16 + s * 8 + lr8) * K + kt + lg, &Bs[bb][wave * 16 + s * 8][0]);
    };

    stage(0, 0);
    int cur = 0;
    for (int kt = 0; kt < K; kt += 64) {
        __syncthreads();
        if (kt + 64 < K) stage(cur ^ 1, kt + 64);
        bf16x8 af[2][4], bfr[2][2];
        #pragma unroll
        for (int kk = 0; kk < 2; kk++) {
            #pragma unroll
            for (int i = 0; i < 4; i++)
                af[kk][i] = *reinterpret_cast<const bf16x8*>(&As[cur][wm + i * 16 + lm][co[kk]]);
            #pragma unroll
            for (int j = 0; j < 2; j++)
                bfr[kk][j] = *reinterpret_cast<const bf16x8*>(&Bs[cur][wn + j * 16 + lm][co[kk]]);
        }
        #pragma unroll
        for (int kk = 0; kk < 2; kk++)
            #pragma unroll
            for (int i = 0; i < 4; i++)
                #pragma unroll
                for (int j = 0; j < 2; j++)
                    acc[i][j] = MFMA_BF16(af[kk][i], bfr[kk][j], acc[i][j]);
        cur ^= 1;
    }

    const int r0 = bm + wm, c0 = bn + wn;
    #pragma unroll
    for (int i = 0; i < 4; i++)
        #pragma unroll
        for (int j = 0; j < 2; j++)
            #pragma unroll
            for (int e = 0; e < 4; e++) {
                const int row = r0 + i * 16 + lq * 4 + e;
                const int col = c0 + j * 16 + lm;
                const size_t idx = (size_t)row * N + col;
                outf[idx] = resid[idx] + acc[i][j][e];
            }
}

// ---------------- Flash attention, causal, hd=64, T=2048, H=16 ----------------
// grid (16 pairs, 16 heads, 2 batch), block 256; each block does qt = 31-bx then qt = bx
// Fixed-shift softmax (M=0); row-sum l via MFMA against ones-column B fragment.
__global__ __launch_bounds__(256)
void attn_kernel(const bf16* __restrict__ qkv, const bf16* __restrict__ vt,
                 bf16* __restrict__ y) {
    __shared__ bf16 Ks[64][68];        // [key][hd]; stride 34 dw -> 2-way max on b128
    __shared__ bf16 Vt[64][68];        // [hd][key]
    __shared__ bf16 Ps[4][16][68];     // per-wave P tile [qrow][key]
    const int tid = threadIdx.x, wave = tid >> 6, lane = tid & 63;
    const int lm = lane & 15, lq = lane >> 4;
    const int h = blockIdx.y, b = blockIdx.z;
    const size_t base = (size_t)b * 2048 * 3072;
    const bf16* Kbase = qkv + base + 1024 + h * 64;
    const bf16* Vbase = vt + ((size_t)(b * 16 + h) * 64) * 2048;
    const int skey = tid >> 3, sch = (tid & 7) * 8;
    const float k1 = 0.18033688011112042f;   // 0.125 * log2(e)

    bf16x8 ones;
    #pragma unroll
    for (int j = 0; j < 8; j++) ones[j] = (lm == 0) ? (bf16)1.0f : (bf16)0.0f;

    for (int ph = 0; ph < 2; ph++) {
        const int qt = ph ? (int)blockIdx.x : 31 - (int)blockIdx.x;

        const int qrow = qt * 64 + wave * 16 + lm;
        const bf16* qp = qkv + base + (size_t)qrow * 3072 + h * 64 + lq * 8;
        bf16x8 aq0 = *reinterpret_cast<const bf16x8*>(qp);
        bf16x8 aq1 = *reinterpret_cast<const bf16x8*>(qp + 32);
        #pragma unroll
        for (int j = 0; j < 8; j++) {
            aq0[j] = (bf16)((float)aq0[j] * k1);
            aq1[j] = (bf16)((float)aq1[j] * k1);
        }

        f32x4 Oc[4], Ol;
        #pragma unroll
        for (int nt = 0; nt < 4; nt++) Oc[nt] = (f32x4){0.f, 0.f, 0.f, 0.f};
        Ol = (f32x4){0.f, 0.f, 0.f, 0.f};

        bf16x8 pk0, pk1, pv0, pv1;
        {   // prefetch tile 0
            const bf16* kp = Kbase + (size_t)skey * 3072 + sch;
            pk0 = *reinterpret_cast<const bf16x8*>(kp);
            pk1 = *reinterpret_cast<const bf16x8*>(kp + (size_t)32 * 3072);
            const bf16* vp = Vbase + (size_t)skey * 2048 + sch;
            pv0 = *reinterpret_cast<const bf16x8*>(vp);
            pv1 = *reinterpret_cast<const bf16x8*>(vp + (size_t)32 * 2048);
        }

        for (int kt2 = 0; kt2 <= qt; kt2++) {
            __syncthreads();   // previous iteration/phase LDS reads complete
            *reinterpret_cast<bf16x8*>(&Ks[skey][sch])      = pk0;
            *reinterpret_cast<bf16x8*>(&Ks[skey + 32][sch]) = pk1;
            *reinterpret_cast<bf16x8*>(&Vt[skey][sch])      = pv0;
            *reinterpret_cast<bf16x8*>(&Vt[skey + 32][sch]) = pv1;
            __syncthreads();
            if (kt2 < qt) {   // next-tile loads overlap compute
                const bf16* kp = Kbase + (size_t)((kt2 + 1) * 64 + skey) * 3072 + sch;
                pk0 = *reinterpret_cast<const bf16x8*>(kp);
                pk1 = *reinterpret_cast<const bf16x8*>(kp + (size_t)32 * 3072);
                const bf16* vp = Vbase + (size_t)skey * 2048 + (kt2 + 1) * 64 + sch;
                pv0 = *reinterpret_cast<const bf16x8*>(vp);
                pv1 = *reinterpret_cast<const bf16x8*>(vp + (size_t)32 * 2048);
            }

            f32x4 Sc[4];
            #pragma unroll
            for (int nt = 0; nt < 4; nt++) Sc[nt] = (f32x4){0.f, 0.f, 0.f, 0.f};
            #pragma unroll
            for (int nt = 0; nt < 4; nt++) {
                const bf16x8 bk0 = *reinterpret_cast<const bf16x8*>(&Ks[nt * 16 + lm][lq * 8]);
                const bf16x8 bk1 = *reinterpret_cast<const bf16x8*>(&Ks[nt * 16 + lm][32 + lq * 8]);
                Sc[nt] = MFMA_BF16(aq0, bk0, Sc[nt]);
                Sc[nt] = MFMA_BF16(aq1, bk1, Sc[nt]);
            }

            // fixed-shift softmax: p = exp2(score); masked -> 0
            const int qb = wave * 16 + lq * 4;
            #pragma unroll
            for (int e = 0; e < 4; e++) {
                #pragma unroll
                for (int nt = 0; nt < 4; nt++) {
                    float sv = Sc[nt][e];
                    if (kt2 == qt && (nt * 16 + lm) > (qb + e)) sv = -1e30f;
                    Ps[wave][lq * 4 + e][nt * 16 + lm] = (bf16)exp2f(sv);
                }
            }

            const bf16x8 ap0 = *reinterpret_cast<const bf16x8*>(&Ps[wave][lm][lq * 8]);
            const bf16x8 ap1 = *reinterpret_cast<const bf16x8*>(&Ps[wave][lm][32 + lq * 8]);
            Ol = MFMA_BF16(ap0, ones, Ol);      // row-sum l into column 0
            Ol = MFMA_BF16(ap1, ones, Ol);
            #pragma unroll
            for (int nt = 0; nt < 4; nt++) {
                const bf16x8 bv0 = *reinterpret_cast<const bf16x8*>(&Vt[nt * 16 + lm][lq * 8]);
                const bf16x8 bv1 = *reinterpret_cast<const bf16x8*>(&Vt[nt * 16 + lm][32 + lq * 8]);
                Oc[nt] = MFMA_BF16(ap0, bv0, Oc[nt]);
                Oc[nt] = MFMA_BF16(ap1, bv1, Oc[nt]);
            }
        }

        const int qrow0 = qt * 64 + wave * 16 + lq * 4;
        float inv[4];
        #pragma unroll
        for (int e = 0; e < 4; e++) inv[e] = 1.0f / __shfl(Ol[e], lane & 48);
        #pragma unroll
        for (int nt = 0; nt < 4; nt++)
            #pragma unroll
            for (int e = 0; e < 4; e++) {
                const int row = qrow0 + e;
                y[((size_t)b * 2048 + row) * 1024 + h * 64 + nt * 16 + lm] = (bf16)(Oc[nt][e] * inv[e]);
            }
    }
}

// ---------------- launcher ----------------
extern "C" void kernel_launch(void* const* d_in, const int* in_sizes, int n_in,
                              void* d_out, int out_size, void* d_ws, size_t ws_size,
                              hipStream_t stream) {
    const float* x     = (const float*)d_in[0];
    const float* Wqkv  = (const float*)d_in[1];
    const float* Wproj = (const float*)d_in[2];
    const float* Wfc1  = (const float*)d_in[3];
    const float* Wfc2  = (const float*)d_in[4];
    const float* ln1g  = (const float*)d_in[5];
    const float* ln1b  = (const float*)d_in[6];
    const float* ln2g  = (const float*)d_in[7];
    const float* ln2b  = (const float*)d_in[8];
    float* out = (float*)d_out;
    char* ws = (char*)d_ws;

    bf16*  Wqkvt  = (bf16*)(ws);                  //  6 MB [3072][1024]
    bf16*  Wprojt = (bf16*)(ws + 6291456);        //  2 MB [1024][1024]
    bf16*  Wfc1t  = (bf16*)(ws + 8388608);        //  8 MB [4096][1024]
    bf16*  Wfc2t  = (bf16*)(ws + 16777216);       //  8 MB [1024][4096]
    bf16*  hb     = (bf16*)(ws + 25165824);       //  8 MB LN out; dead after qkv GEMM
    bf16*  vt     = (bf16*)(ws + 25165824);       //  8 MB V^T (aliases hb; reused for LN2)
    bf16*  qkv    = (bf16*)(ws + 33554432);       // 24 MB [4096][3072]
    bf16*  yb     = (bf16*)(ws + 58720256);       //  8 MB attn out [4096][1024]
    float* x1     = (float*)(ws + 67108864);      // 16 MB residual fp32
    bf16*  h3     = (bf16*)(ws + 33554432);       // 32 MB gelu out (aliases dead qkv+yb)

    const dim3 tb(32, 8);
    transpose_cast<<<dim3(96, 32), tb, 0, stream>>>(Wqkv, Wqkvt, 1024, 3072);
    transpose_cast<<<dim3(32, 32), tb, 0, stream>>>(Wproj, Wprojt, 1024, 1024);
    transpose_cast<<<dim3(128, 32), tb, 0, stream>>>(Wfc1, Wfc1t, 1024, 4096);
    transpose_cast<<<dim3(32, 128), tb, 0, stream>>>(Wfc2, Wfc2t, 4096, 1024);

    ln_kernel<<<dim3(4096), dim3(256), 0, stream>>>(x, ln1g, ln1b, hb);
    gemm_bt<0><<<dim3(24, 32), dim3(256), 0, stream>>>(hb, Wqkvt, qkv, 4096, 3072, 1024);
    transpose_v<<<dim3(64, 2, 32), tb, 0, stream>>>(qkv, vt);
    attn_kernel<<<dim3(16, 16, 2), dim3(256), 0, stream>>>(qkv, vt, yb);
    gemm_bt64<<<dim3(16, 32), dim3(256), 0, stream>>>(yb, Wprojt, x, x1, 4096, 1024, 1024);
    ln_kernel<<<dim3(4096), dim3(256), 0, stream>>>(x1, ln2g, ln2b, hb);
    gemm_bt<2><<<dim3(32, 32), dim3(256), 0, stream>>>(hb, Wfc1t, h3, 4096, 4096, 1024);
    gemm_bt64<<<dim3(16, 32), dim3(256), 0, stream>>>(h3, Wfc2t, x1, out, 4096, 1024, 4096);
}